// Round 6
// baseline (405.763 us; speedup 1.0000x reference)
//
#include <hip/hip_runtime.h>

// Pipeline (all bf16 MFMA):
//   1. prep_kernel: fused x fp32->bf16 + W_Q/K/V -> [h*64+e][d] (concat 3072) + W_O -> [d][n]
//   2. gemm_qkv: fused GEMM N=3072. Q/K computed as C^T (operand swap) so epilogue packs
//      4 consecutive e per lane -> ushort4 stores (was 64x 2B scatter). V unswapped
//      (rg runs along s -> ushort4 into (B,H,DH,S)). Q scaled by 0.125*log2e.
//   3. attn_kernel: causal flash attention, FUSED q-tile pairs {y, 15-y} in ONE kt loop:
//      staging 16-y tiles (was 17) while compute stays uniform 17 group-iters/block.
//      C=0 softmax, raw v_exp_f32 + v_perm packing, sV padded-linear stride 140,
//      sK g2lds dbuf, XCD-local grid (bh fast dim).
//   4. gemm_o: C^T operand swap -> 16x float4 stores.

#define B_ 4
#define S_ 2048
#define D_ 1024
#define H_ 16
#define DH_ 64

typedef unsigned short ushort_t;
typedef __attribute__((ext_vector_type(4))) short short4v;
typedef __attribute__((ext_vector_type(8))) short short8v;
typedef __attribute__((ext_vector_type(4))) float floatx4;
typedef __attribute__((ext_vector_type(4))) unsigned short ushort4v;

static __device__ __forceinline__ ushort_t f2bf(float f) {
    union { float f; unsigned u; } v; v.f = f;
    unsigned r = v.u + 0x7fffu + ((v.u >> 16) & 1u);  // RNE
    return (ushort_t)(r >> 16);
}

static __device__ __forceinline__ float fast_exp2(float x) {
#if __has_builtin(__builtin_amdgcn_exp2f)
    return __builtin_amdgcn_exp2f(x);   // raw v_exp_f32
#else
    return exp2f(x);
#endif
}

// pack trunc-bf16(lo), trunc-bf16(hi) into one dword via v_perm_b32
static __device__ __forceinline__ unsigned pack_bf16_tr(float lo, float hi) {
    union { float f; unsigned u; } a, b;
    a.f = lo; b.f = hi;
    return __builtin_amdgcn_perm(b.u, a.u, 0x07060302u);
}

// async global(16B/lane) -> LDS (uniform base + lane*16)
static __device__ __forceinline__ void g2lds16(const void* g, void* l) {
    __builtin_amdgcn_global_load_lds(
        (__attribute__((address_space(1))) void*)(unsigned long long)(size_t)g,
        (__attribute__((address_space(3))) void*)(unsigned int)(size_t)l,
        16, 0, 0);
}

// ---------------- 1. fused prep: convert x + transpose weights ----------------
__global__ void prep_kernel(const float* __restrict__ x,
                            const float* __restrict__ wq, const float* __restrict__ wk,
                            const float* __restrict__ wv, const float* __restrict__ wo,
                            ushort_t* __restrict__ xb, ushort_t* __restrict__ wt,
                            ushort_t* __restrict__ wot) {
    __shared__ float tile[32][33];
    int bid = blockIdx.x;
    int tid = threadIdx.x;
    if (bid < 8192) {
        int i = (bid * 256 + tid) * 4;
        float4 v = *(const float4*)&x[i];
        ushort4v o;
        o[0] = f2bf(v.x); o[1] = f2bf(v.y); o[2] = f2bf(v.z); o[3] = f2bf(v.w);
        *(ushort4v*)&xb[i] = o;
        return;
    }
    const float* src;
    ushort_t* d;
    int C, r0, c0;
    if (bid < 11264) {
        int t = bid - 8192;
        int z = t / 64, r = t % 64;
        src = (z < 16 ? wq : (z < 32 ? wk : wv)) + (size_t)(z & 15) * 65536;
        d = wt + (size_t)z * 65536;
        C = 64; r0 = (r >> 1) * 32; c0 = (r & 1) * 32;
    } else {
        int t = bid - 11264;
        int z = t / 64, r = t % 64;
        src = wo + (size_t)z * 65536;
        d = wot + (size_t)z * 64;
        C = 1024; r0 = (r & 1) * 32; c0 = (r >> 1) * 32;
    }
    int tx = tid & 31, ty = tid >> 5;
#pragma unroll
    for (int i = 0; i < 4; ++i)
        tile[ty + i * 8][tx] = src[(size_t)(r0 + ty + i * 8) * C + c0 + tx];
    __syncthreads();
#pragma unroll
    for (int i = 0; i < 4; ++i)
        d[(size_t)(c0 + ty + i * 8) * 1024 + r0 + tx] = f2bf(tile[tx][ty + i * 8]);
}

// ---------------- 2. fused QKV GEMM ----------------
// grid (64 m-tiles, 24 n-tiles), XCD-local in m. Q/K: operand-swapped (C^T). V: direct.
__global__ __launch_bounds__(256) void gemm_qkv(const ushort_t* __restrict__ A,
                                                const ushort_t* __restrict__ Wt,
                                                const float* __restrict__ bq,
                                                const float* __restrict__ bk,
                                                const float* __restrict__ bv,
                                                ushort_t* __restrict__ Qw,
                                                ushort_t* __restrict__ Kw,
                                                ushort_t* __restrict__ Vw) {
    __shared__ ushort_t sA[128 * 64];
    __shared__ ushort_t sB[128 * 64];
    const int tid = threadIdx.x;
    const int lane = tid & 63, w = tid >> 6;
    const int lq = lane & 15, quad = lane >> 4;
    const int wm = w >> 1, wn = w & 1;
    const int m0 = blockIdx.x * 128, n0 = blockIdx.y * 128;
    const int mat = blockIdx.y >> 3;

    // frag partition: V (mat==2) direct (rows=m); Q/K swapped (rows=n)
    const int rsa = (mat == 2 ? wm : wn);   // sA wave-quadrant
    const int rsb = (mat == 2 ? wn : wm);   // sB wave-quadrant

    floatx4 acc[4][4] = {};

    for (int k0 = 0; k0 < 1024; k0 += 64) {
        __syncthreads();
#pragma unroll
        for (int p = 0; p < 4; ++p) {
            int rr = w * 32 + p * 8 + (lane >> 3);
            int cc = (lane & 7) ^ (rr & 7);
            g2lds16(&A[(size_t)(m0 + rr) * 1024 + k0 + cc * 8], &sA[(w * 32 + p * 8) * 64]);
            g2lds16(&Wt[(size_t)(n0 + rr) * 1024 + k0 + cc * 8], &sB[(w * 32 + p * 8) * 64]);
        }
        __syncthreads();
#pragma unroll
        for (int ks = 0; ks < 2; ++ks) {
            short8v af[4], bfr[4];
#pragma unroll
            for (int t = 0; t < 4; ++t) {
                int ma = rsa * 64 + t * 16 + lq;
                af[t] = *(const short8v*)&sA[ma * 64 + ((((ks << 2) | quad) ^ (ma & 7)) << 3)];
                int nb = rsb * 64 + t * 16 + lq;
                bfr[t] = *(const short8v*)&sB[nb * 64 + ((((ks << 2) | quad) ^ (nb & 7)) << 3)];
            }
            if (mat == 2) {
#pragma unroll
                for (int mt = 0; mt < 4; ++mt)
#pragma unroll
                    for (int nt = 0; nt < 4; ++nt)
                        acc[mt][nt] = __builtin_amdgcn_mfma_f32_16x16x32_bf16(af[mt], bfr[nt], acc[mt][nt], 0, 0, 0);
            } else {
#pragma unroll
                for (int mt = 0; mt < 4; ++mt)
#pragma unroll
                    for (int nt = 0; nt < 4; ++nt)
                        acc[mt][nt] = __builtin_amdgcn_mfma_f32_16x16x32_bf16(bfr[mt], af[nt], acc[mt][nt], 0, 0, 0);
            }
        }
    }

    if (mat == 2) {
        // rows = m (s), cols = n (h,e); rg along s -> ushort4 into (B,H,DH,S)
        float bias_v[4];
#pragma unroll
        for (int nt = 0; nt < 4; ++nt) bias_v[nt] = bv[(n0 & 1023) + wn * 64 + nt * 16 + lq];
#pragma unroll
        for (int mt = 0; mt < 4; ++mt) {
#pragma unroll
            for (int nt = 0; nt < 4; ++nt) {
                int row0 = m0 + wm * 64 + mt * 16 + quad * 4;
                int col = (n0 & 1023) + wn * 64 + nt * 16 + lq;
                int b = row0 >> 11, s = row0 & 2047;
                int h = col >> 6, e = col & 63;
                ushort4v pk;
#pragma unroll
                for (int rg = 0; rg < 4; ++rg) pk[rg] = f2bf(acc[mt][nt][rg] + bias_v[nt]);
                *(ushort4v*)&Vw[((size_t)((b << 4) | h) * 64 + e) * 2048 + s] = pk;
            }
        }
    } else {
        // swapped: rows = n (h,e), cols = m (s); rg along e -> ushort4 into (B,H,S,DH)
        ushort_t* Du = mat == 0 ? Qw : Kw;
        const float* bias = mat == 0 ? bq : bk;
        const float sc = mat == 0 ? 0.18033688011112042f : 1.0f;  // (1/8)*log2(e) on Q
#pragma unroll
        for (int mt = 0; mt < 4; ++mt) {
            int nbase = (n0 & 1023) + wm * 64 + mt * 16 + quad * 4;
            float4 bvv = *(const float4*)&bias[nbase];
            float bb[4] = {bvv.x, bvv.y, bvv.z, bvv.w};
            int h = nbase >> 6, e = nbase & 63;
#pragma unroll
            for (int nt = 0; nt < 4; ++nt) {
                int m = m0 + wn * 64 + nt * 16 + lq;
                int b = m >> 11, s = m & 2047;
                ushort4v pk;
#pragma unroll
                for (int rg = 0; rg < 4; ++rg) pk[rg] = f2bf((acc[mt][nt][rg] + bb[rg]) * sc);
                *(ushort4v*)&Du[((size_t)((b << 4) | h) * 2048 + s) * 64 + e] = pk;
            }
        }
    }
}

// ---------------- 3. causal flash attention, fused q-tile pairs ----------------
// grid (64 bh, 8 y); block handles q-tiles {y, 15-y} in ONE kt loop (kt=0..15-y).
// Compute = uniform 17 group-iters/block; staging = 16-y tiles.
#define VROW 140
__global__ __launch_bounds__(256, 2) void attn_kernel(const ushort_t* __restrict__ Q,
                                                      const ushort_t* __restrict__ Kg,
                                                      const ushort_t* __restrict__ Vt,
                                                      ushort_t* __restrict__ Z) {
    __shared__ ushort_t sK[2][128 * 64];
    __shared__ ushort_t sV[64 * VROW];
    const int tid = threadIdx.x;
    const int lane = tid & 63, w = tid >> 6;
    const int lq = lane & 15, quad = lane >> 4;
    const int bh = blockIdx.x;
    const int y = blockIdx.y;
    const int qtA = y, qtB = 15 - y;
    const int q0A = qtA * 128, q0B = qtB * 128;
    const int b = bh >> 4, h = bh & 15;
    const ushort_t* Qp = Q + (size_t)bh * S_ * DH_;
    const ushort_t* Kp = Kg + (size_t)bh * S_ * DH_;
    const ushort_t* Vp = Vt + (size_t)bh * DH_ * S_;

    const int kbase0 = lq * 64 + ((quad ^ (lq & 7)) << 3);
    const int kbase1 = lq * 64 + (((4 | quad) ^ (lq & 7)) << 3);
    const int vbase = lq * VROW + quad * 4;
    const int vr = w * 16 + (lane >> 2);
    const int vc = (lane & 3) * 32;

    const floatx4 fzero = {0.f, 0.f, 0.f, 0.f};

    auto stageK = [&](int kt, int bs) __attribute__((always_inline)) {
        ushort_t* dK = sK[bs];
#pragma unroll
        for (int p = 0; p < 4; ++p) {
            int rrk = w * 32 + p * 8 + (lane >> 3);
            int ck = (lane & 7) ^ (rrk & 7);
            g2lds16(&Kp[(size_t)(kt * 128 + rrk) * 64 + ck * 8], &dK[(w * 32 + p * 8) * 64]);
        }
    };
    auto loadV = [&](int kt, short8v* vr4) __attribute__((always_inline)) {
        const ushort_t* src = &Vp[(size_t)vr * 2048 + kt * 128 + vc];
#pragma unroll
        for (int j = 0; j < 4; ++j) vr4[j] = *(const short8v*)&src[j * 8];
    };
    auto writeV = [&](const short8v* vr4) __attribute__((always_inline)) {
        ushort_t* dst = &sV[vr * VROW + vc];
#pragma unroll
        for (int j = 0; j < 4; ++j) *(short8v*)&dst[j * 8] = vr4[j];
    };

    // 4 q-strips: 0,1 -> tile A; 2,3 -> tile B
    short8v qf[4][2];
#pragma unroll
    for (int s4 = 0; s4 < 4; ++s4) {
        int qrow = (s4 < 2 ? q0A : q0B) + w * 32 + (s4 & 1) * 16 + lq;
#pragma unroll
        for (int ks = 0; ks < 2; ++ks)
            qf[s4][ks] = *(const short8v*)&Qp[(size_t)qrow * DH_ + ks * 32 + quad * 8];
    }

    float l_i[4] = {0.f, 0.f, 0.f, 0.f};
    floatx4 o[4][4] = {};
    short8v vreg[4];

    stageK(0, 0);
    loadV(0, vreg);

    for (int kt = 0; kt <= qtB; ++kt) {
        const ushort_t* cK = sK[kt & 1];

        __syncthreads();           // prev PV done; K(kt) g2lds + V(kt) loads drained
        writeV(vreg);
        if (kt < qtB) {
            stageK(kt + 1, (kt + 1) & 1);
            loadV(kt + 1, vreg);
        }

        // group scores: St = K*Q^T, softmax -> pf (A-frag layout, zero movement)
        auto score = [&](int g, bool diag, int q0, short4v (*pf)[2]) __attribute__((always_inline)) {
            floatx4 st[8][2];
#pragma unroll
            for (int si = 0; si < 8; ++si) {
                short8v a0 = *(const short8v*)&cK[kbase0 + si * 1024];
                short8v a1 = *(const short8v*)&cK[kbase1 + si * 1024];
#pragma unroll
                for (int j = 0; j < 2; ++j) {
                    st[si][j] = __builtin_amdgcn_mfma_f32_16x16x32_bf16(a0, qf[g + j][0], fzero, 0, 0, 0);
                    st[si][j] = __builtin_amdgcn_mfma_f32_16x16x32_bf16(a1, qf[g + j][1], st[si][j], 0, 0, 0);
                }
            }
#pragma unroll
            for (int j = 0; j < 2; ++j) {
                const int qg = q0 + w * 32 + j * 16 + lq;
                float lsum = 0.f;
#pragma unroll
                for (int si = 0; si < 8; ++si) {
                    float p[4];
#pragma unroll
                    for (int rg = 0; rg < 4; ++rg) {
                        float v = st[si][j][rg];
                        if (diag) {
                            int sg = kt * 128 + si * 16 + quad * 4 + rg;
                            if (sg > qg) v = -1e30f;
                        }
                        p[rg] = fast_exp2(v);
                        lsum += p[rg];
                    }
                    union { unsigned u[2]; short4v v4; } pk;
                    pk.u[0] = pack_bf16_tr(p[0], p[1]);
                    pk.u[1] = pack_bf16_tr(p[2], p[3]);
                    pf[si][j] = pk.v4;
                }
                l_i[g + j] += lsum;
            }
        };
        auto pv = [&](int g, const short4v (*pf)[2]) __attribute__((always_inline)) {
#pragma unroll
            for (int ksp = 0; ksp < 8; ++ksp) {
#pragma unroll
                for (int et = 0; et < 4; ++et) {
                    short4v vf = *(const short4v*)&sV[vbase + et * (16 * VROW) + ksp * 16];
#pragma unroll
                    for (int j = 0; j < 2; ++j)
                        o[g + j][et] = __builtin_amdgcn_mfma_f32_16x16x16bf16_1k(pf[ksp][j], vf, o[g + j][et], 0, 0, 0);
                }
            }
        };

        short4v pfB[8][2];
        score(2, kt == qtB, q0B, pfB);
        __syncthreads();           // sV visible
        pv(2, pfB);
        if (kt <= qtA) {
            short4v pfA[8][2];
            score(0, kt == qtA, q0A, pfA);
            pv(0, pfA);
        }
    }

    // epilogue: per-strip l reduce, divide, store Z (B,S,H,DH)
#pragma unroll
    for (int s4 = 0; s4 < 4; ++s4) {
        float lf = l_i[s4];
        lf += __shfl_xor(lf, 16);
        lf += __shfl_xor(lf, 32);
        float linv[4];
#pragma unroll
        for (int rg = 0; rg < 4; ++rg) linv[rg] = 1.0f / __shfl(lf, quad * 4 + rg);
        int q0 = (s4 < 2 ? q0A : q0B) + w * 32 + (s4 & 1) * 16;
#pragma unroll
        for (int et = 0; et < 4; ++et) {
#pragma unroll
            for (int rg = 0; rg < 4; ++rg) {
                int qg = q0 + quad * 4 + rg;
                int e = et * 16 + lq;
                Z[((size_t)(b * S_ + qg) * H_ + h) * DH_ + e] = f2bf(o[s4][et][rg] * linv[rg]);
            }
        }
    }
}

// ---------------- 4. output projection GEMM (operand-swapped, float4 stores) ----------------
__global__ __launch_bounds__(256) void gemm_o(const ushort_t* __restrict__ A,
                                              const ushort_t* __restrict__ Bt,
                                              const float* __restrict__ bias,
                                              float* __restrict__ Dst) {
    __shared__ ushort_t sA[128 * 64];
    __shared__ ushort_t sB[128 * 64];
    const int tid = threadIdx.x;
    const int lane = tid & 63, w = tid >> 6;
    const int lq = lane & 15, quad = lane >> 4;
    const int wm = w >> 1, wn = w & 1;
    const int m0 = blockIdx.x * 128, n0 = blockIdx.y * 128;

    floatx4 acc[4][4] = {};

    for (int k0 = 0; k0 < 1024; k0 += 64) {
        __syncthreads();
#pragma unroll
        for (int p = 0; p < 4; ++p) {
            int rr = w * 32 + p * 8 + (lane >> 3);
            int cc = (lane & 7) ^ (rr & 7);
            g2lds16(&A[(size_t)(m0 + rr) * 1024 + k0 + cc * 8], &sA[(w * 32 + p * 8) * 64]);
            g2lds16(&Bt[(size_t)(n0 + rr) * 1024 + k0 + cc * 8], &sB[(w * 32 + p * 8) * 64]);
        }
        __syncthreads();
#pragma unroll
        for (int ks = 0; ks < 2; ++ks) {
            short8v af[4], bfr[4];
#pragma unroll
            for (int t = 0; t < 4; ++t) {
                int ma = wn * 64 + t * 16 + lq;   // m-side partitioned by wn (swapped)
                af[t] = *(const short8v*)&sA[ma * 64 + ((((ks << 2) | quad) ^ (ma & 7)) << 3)];
                int nb = wm * 64 + t * 16 + lq;   // n-side partitioned by wm
                bfr[t] = *(const short8v*)&sB[nb * 64 + ((((ks << 2) | quad) ^ (nb & 7)) << 3)];
            }
#pragma unroll
            for (int mt = 0; mt < 4; ++mt)
#pragma unroll
                for (int nt = 0; nt < 4; ++nt)
                    acc[mt][nt] = __builtin_amdgcn_mfma_f32_16x16x32_bf16(bfr[mt], af[nt], acc[mt][nt], 0, 0, 0);
        }
    }

    // rows = n (d), cols = m (s); rg along d -> float4 stores
#pragma unroll
    for (int mt = 0; mt < 4; ++mt) {
        int nbase = n0 + wm * 64 + mt * 16 + quad * 4;
        float4 bvv = *(const float4*)&bias[nbase];
        float bb[4] = {bvv.x, bvv.y, bvv.z, bvv.w};
#pragma unroll
        for (int nt = 0; nt < 4; ++nt) {
            int m = m0 + wn * 64 + nt * 16 + lq;
            float4 ov;
            ov.x = acc[mt][nt][0] + bb[0];
            ov.y = acc[mt][nt][1] + bb[1];
            ov.z = acc[mt][nt][2] + bb[2];
            ov.w = acc[mt][nt][3] + bb[3];
            *(float4*)&Dst[(size_t)m * 1024 + nbase] = ov;
        }
    }
}

extern "C" void kernel_launch(void* const* d_in, const int* in_sizes, int n_in,
                              void* d_out, int out_size, void* d_ws, size_t ws_size,
                              hipStream_t stream) {
    const float* x  = (const float*)d_in[0];
    const float* wq = (const float*)d_in[1];
    const float* bq = (const float*)d_in[2];
    const float* wk = (const float*)d_in[3];
    const float* bk = (const float*)d_in[4];
    const float* wv = (const float*)d_in[5];
    const float* bv = (const float*)d_in[6];
    const float* wo = (const float*)d_in[7];
    const float* bo = (const float*)d_in[8];

    char* ws = (char*)d_ws;
    size_t off = 0;
    ushort_t* xb  = (ushort_t*)(ws + off); off += (size_t)8192 * 1024 * 2;
    ushort_t* wt  = (ushort_t*)(ws + off); off += (size_t)3 * 1024 * 1024 * 2;
    ushort_t* wot = (ushort_t*)(ws + off); off += (size_t)1024 * 1024 * 2;
    ushort_t* Qw  = (ushort_t*)(ws + off); off += (size_t)8192 * 1024 * 2;
    ushort_t* Kw  = (ushort_t*)(ws + off); off += (size_t)8192 * 1024 * 2;
    ushort_t* Vw  = (ushort_t*)(ws + off); off += (size_t)8192 * 1024 * 2;
    ushort_t* Zw  = (ushort_t*)(ws + off); off += (size_t)8192 * 1024 * 2;

    prep_kernel<<<12288, 256, 0, stream>>>(x, wq, wk, wv, wo, xb, wt, wot);
    gemm_qkv<<<dim3(64, 24), 256, 0, stream>>>(xb, wt, bq, bk, bv, Qw, Kw, Vw);
    attn_kernel<<<dim3(64, 8), 256, 0, stream>>>(Qw, Kw, Vw, Zw);
    gemm_o<<<dim3(64, 8), 256, 0, stream>>>(Zw, wot, bo, (float*)d_out);
}

// Round 7
// 257.227 us; speedup vs baseline: 1.5775x; 1.5775x over previous
//
#include <hip/hip_runtime.h>

// Pipeline (all bf16 MFMA):
//   1. prep_kernel: fused x fp32->bf16 + W_Q/K/V -> [h*64+e][d] (concat 3072) + W_O -> [d][n]
//   2. gemm_qkv: fused GEMM N=3072. Q/K computed as C^T (operand swap) -> ushort4 epilogue
//      stores. V direct (rg along s -> ushort4 into (B,H,DH,S)). Q scaled by 0.125*log2e.
//   3. attn_kernel: R5 structure (R6's fused q-pair spilled: 516 MB scratch WRITE_SIZE).
//      Two-pass pairs {y,15-y}, C=0 softmax, raw v_exp_f32 + v_perm packing,
//      sV padded-linear stride 140 (uniform 2-way = free), sK g2lds dbuf,
//      XCD-local grid (bh fast dim).
//   4. gemm_o: C^T operand swap -> float4 stores.

#define B_ 4
#define S_ 2048
#define D_ 1024
#define H_ 16
#define DH_ 64

typedef unsigned short ushort_t;
typedef __attribute__((ext_vector_type(4))) short short4v;
typedef __attribute__((ext_vector_type(8))) short short8v;
typedef __attribute__((ext_vector_type(4))) float floatx4;
typedef __attribute__((ext_vector_type(4))) unsigned short ushort4v;

static __device__ __forceinline__ ushort_t f2bf(float f) {
    union { float f; unsigned u; } v; v.f = f;
    unsigned r = v.u + 0x7fffu + ((v.u >> 16) & 1u);  // RNE
    return (ushort_t)(r >> 16);
}

static __device__ __forceinline__ float fast_exp2(float x) {
#if __has_builtin(__builtin_amdgcn_exp2f)
    return __builtin_amdgcn_exp2f(x);   // raw v_exp_f32
#else
    return exp2f(x);
#endif
}

// pack trunc-bf16(lo), trunc-bf16(hi) into one dword via v_perm_b32
static __device__ __forceinline__ unsigned pack_bf16_tr(float lo, float hi) {
    union { float f; unsigned u; } a, b;
    a.f = lo; b.f = hi;
    return __builtin_amdgcn_perm(b.u, a.u, 0x07060302u);
}

// async global(16B/lane) -> LDS (uniform base + lane*16)
static __device__ __forceinline__ void g2lds16(const void* g, void* l) {
    __builtin_amdgcn_global_load_lds(
        (__attribute__((address_space(1))) void*)(unsigned long long)(size_t)g,
        (__attribute__((address_space(3))) void*)(unsigned int)(size_t)l,
        16, 0, 0);
}

// ---------------- 1. fused prep: convert x + transpose weights ----------------
__global__ void prep_kernel(const float* __restrict__ x,
                            const float* __restrict__ wq, const float* __restrict__ wk,
                            const float* __restrict__ wv, const float* __restrict__ wo,
                            ushort_t* __restrict__ xb, ushort_t* __restrict__ wt,
                            ushort_t* __restrict__ wot) {
    __shared__ float tile[32][33];
    int bid = blockIdx.x;
    int tid = threadIdx.x;
    if (bid < 8192) {
        int i = (bid * 256 + tid) * 4;
        float4 v = *(const float4*)&x[i];
        ushort4v o;
        o[0] = f2bf(v.x); o[1] = f2bf(v.y); o[2] = f2bf(v.z); o[3] = f2bf(v.w);
        *(ushort4v*)&xb[i] = o;
        return;
    }
    const float* src;
    ushort_t* d;
    int C, r0, c0;
    if (bid < 11264) {
        int t = bid - 8192;
        int z = t / 64, r = t % 64;
        src = (z < 16 ? wq : (z < 32 ? wk : wv)) + (size_t)(z & 15) * 65536;
        d = wt + (size_t)z * 65536;
        C = 64; r0 = (r >> 1) * 32; c0 = (r & 1) * 32;
    } else {
        int t = bid - 11264;
        int z = t / 64, r = t % 64;
        src = wo + (size_t)z * 65536;
        d = wot + (size_t)z * 64;
        C = 1024; r0 = (r & 1) * 32; c0 = (r >> 1) * 32;
    }
    int tx = tid & 31, ty = tid >> 5;
#pragma unroll
    for (int i = 0; i < 4; ++i)
        tile[ty + i * 8][tx] = src[(size_t)(r0 + ty + i * 8) * C + c0 + tx];
    __syncthreads();
#pragma unroll
    for (int i = 0; i < 4; ++i)
        d[(size_t)(c0 + ty + i * 8) * 1024 + r0 + tx] = f2bf(tile[tx][ty + i * 8]);
}

// ---------------- 2. fused QKV GEMM ----------------
// grid (64 m-tiles, 24 n-tiles), XCD-local in m. Q/K: operand-swapped (C^T). V: direct.
__global__ __launch_bounds__(256) void gemm_qkv(const ushort_t* __restrict__ A,
                                                const ushort_t* __restrict__ Wt,
                                                const float* __restrict__ bq,
                                                const float* __restrict__ bk,
                                                const float* __restrict__ bv,
                                                ushort_t* __restrict__ Qw,
                                                ushort_t* __restrict__ Kw,
                                                ushort_t* __restrict__ Vw) {
    __shared__ ushort_t sA[128 * 64];
    __shared__ ushort_t sB[128 * 64];
    const int tid = threadIdx.x;
    const int lane = tid & 63, w = tid >> 6;
    const int lq = lane & 15, quad = lane >> 4;
    const int wm = w >> 1, wn = w & 1;
    const int m0 = blockIdx.x * 128, n0 = blockIdx.y * 128;
    const int mat = blockIdx.y >> 3;

    const int rsa = (mat == 2 ? wm : wn);
    const int rsb = (mat == 2 ? wn : wm);

    floatx4 acc[4][4] = {};

    for (int k0 = 0; k0 < 1024; k0 += 64) {
        __syncthreads();
#pragma unroll
        for (int p = 0; p < 4; ++p) {
            int rr = w * 32 + p * 8 + (lane >> 3);
            int cc = (lane & 7) ^ (rr & 7);
            g2lds16(&A[(size_t)(m0 + rr) * 1024 + k0 + cc * 8], &sA[(w * 32 + p * 8) * 64]);
            g2lds16(&Wt[(size_t)(n0 + rr) * 1024 + k0 + cc * 8], &sB[(w * 32 + p * 8) * 64]);
        }
        __syncthreads();
#pragma unroll
        for (int ks = 0; ks < 2; ++ks) {
            short8v af[4], bfr[4];
#pragma unroll
            for (int t = 0; t < 4; ++t) {
                int ma = rsa * 64 + t * 16 + lq;
                af[t] = *(const short8v*)&sA[ma * 64 + ((((ks << 2) | quad) ^ (ma & 7)) << 3)];
                int nb = rsb * 64 + t * 16 + lq;
                bfr[t] = *(const short8v*)&sB[nb * 64 + ((((ks << 2) | quad) ^ (nb & 7)) << 3)];
            }
            if (mat == 2) {
#pragma unroll
                for (int mt = 0; mt < 4; ++mt)
#pragma unroll
                    for (int nt = 0; nt < 4; ++nt)
                        acc[mt][nt] = __builtin_amdgcn_mfma_f32_16x16x32_bf16(af[mt], bfr[nt], acc[mt][nt], 0, 0, 0);
            } else {
#pragma unroll
                for (int mt = 0; mt < 4; ++mt)
#pragma unroll
                    for (int nt = 0; nt < 4; ++nt)
                        acc[mt][nt] = __builtin_amdgcn_mfma_f32_16x16x32_bf16(bfr[mt], af[nt], acc[mt][nt], 0, 0, 0);
            }
        }
    }

    if (mat == 2) {
        float bias_v[4];
#pragma unroll
        for (int nt = 0; nt < 4; ++nt) bias_v[nt] = bv[(n0 & 1023) + wn * 64 + nt * 16 + lq];
#pragma unroll
        for (int mt = 0; mt < 4; ++mt) {
#pragma unroll
            for (int nt = 0; nt < 4; ++nt) {
                int row0 = m0 + wm * 64 + mt * 16 + quad * 4;
                int col = (n0 & 1023) + wn * 64 + nt * 16 + lq;
                int b = row0 >> 11, s = row0 & 2047;
                int h = col >> 6, e = col & 63;
                ushort4v pk;
#pragma unroll
                for (int rg = 0; rg < 4; ++rg) pk[rg] = f2bf(acc[mt][nt][rg] + bias_v[nt]);
                *(ushort4v*)&Vw[((size_t)((b << 4) | h) * 64 + e) * 2048 + s] = pk;
            }
        }
    } else {
        ushort_t* Du = mat == 0 ? Qw : Kw;
        const float* bias = mat == 0 ? bq : bk;
        const float sc = mat == 0 ? 0.18033688011112042f : 1.0f;  // (1/8)*log2(e) on Q
#pragma unroll
        for (int mt = 0; mt < 4; ++mt) {
            int nbase = (n0 & 1023) + wm * 64 + mt * 16 + quad * 4;
            float4 bvv = *(const float4*)&bias[nbase];
            float bb[4] = {bvv.x, bvv.y, bvv.z, bvv.w};
            int h = nbase >> 6, e = nbase & 63;
#pragma unroll
            for (int nt = 0; nt < 4; ++nt) {
                int m = m0 + wn * 64 + nt * 16 + lq;
                int b = m >> 11, s = m & 2047;
                ushort4v pk;
#pragma unroll
                for (int rg = 0; rg < 4; ++rg) pk[rg] = f2bf((acc[mt][nt][rg] + bb[rg]) * sc);
                *(ushort4v*)&Du[((size_t)((b << 4) | h) * 2048 + s) * 64 + e] = pk;
            }
        }
    }
}

// ---------------- 3. causal flash attention (R5 structure) ----------------
// grid (64 bh, 8 y); block handles q-tiles {y, 15-y} sequentially (17 kt-iters total).
#define VROW 140   // banks (6*lq+2*quad)%32 -> uniform 2-way (free)
__global__ __launch_bounds__(256) void attn_kernel(const ushort_t* __restrict__ Q,
                                                   const ushort_t* __restrict__ Kg,
                                                   const ushort_t* __restrict__ Vt,
                                                   ushort_t* __restrict__ Z) {
    __shared__ ushort_t sK[2][128 * 64];   // [s][d] XOR-swizzled, g2lds dbuf
    __shared__ ushort_t sV[64 * VROW];     // [e][s] padded-linear, single buffer
    const int tid = threadIdx.x;
    const int lane = tid & 63, w = tid >> 6;
    const int lq = lane & 15, quad = lane >> 4;
    const int bh = blockIdx.x;
    const int b = bh >> 4, h = bh & 15;
    const ushort_t* Qp = Q + (size_t)bh * S_ * DH_;
    const ushort_t* Kp = Kg + (size_t)bh * S_ * DH_;
    const ushort_t* Vp = Vt + (size_t)bh * DH_ * S_;

    const int kbase0 = lq * 64 + ((quad ^ (lq & 7)) << 3);
    const int kbase1 = lq * 64 + (((4 | quad) ^ (lq & 7)) << 3);
    const int vbase = lq * VROW + quad * 4;
    const int vr = w * 16 + (lane >> 2);
    const int vc = (lane & 3) * 32;

    const floatx4 fzero = {0.f, 0.f, 0.f, 0.f};

    auto stageK = [&](int kt, int bs) __attribute__((always_inline)) {
        ushort_t* dK = sK[bs];
#pragma unroll
        for (int p = 0; p < 4; ++p) {
            int rrk = w * 32 + p * 8 + (lane >> 3);
            int ck = (lane & 7) ^ (rrk & 7);
            g2lds16(&Kp[(size_t)(kt * 128 + rrk) * 64 + ck * 8], &dK[(w * 32 + p * 8) * 64]);
        }
    };
    auto loadV = [&](int kt, short8v* vr4) __attribute__((always_inline)) {
        const ushort_t* src = &Vp[(size_t)vr * 2048 + kt * 128 + vc];
#pragma unroll
        for (int j = 0; j < 4; ++j) vr4[j] = *(const short8v*)&src[j * 8];
    };
    auto writeV = [&](const short8v* vr4) __attribute__((always_inline)) {
        ushort_t* dst = &sV[vr * VROW + vc];
#pragma unroll
        for (int j = 0; j < 4; ++j) *(short8v*)&dst[j * 8] = vr4[j];
    };

    for (int pass = 0; pass < 2; ++pass) {
        const int qt = pass == 0 ? (int)blockIdx.y : 15 - (int)blockIdx.y;
        const int q0 = qt * 128;

        short8v qf[2][2];
#pragma unroll
        for (int qi = 0; qi < 2; ++qi)
#pragma unroll
            for (int ks = 0; ks < 2; ++ks)
                qf[qi][ks] = *(const short8v*)&Qp[(size_t)(q0 + w * 32 + qi * 16 + lq) * DH_ + ks * 32 + quad * 8];

        float l_i[2] = {0.f, 0.f};
        floatx4 o[2][4] = {};
        short8v vreg[4];

        stageK(0, 0);
        loadV(0, vreg);

        for (int kt = 0; kt <= qt; ++kt) {
            const bool diag = (kt == qt);
            const ushort_t* cK = sK[kt & 1];

            __syncthreads();           // drains K(kt) g2lds + V(kt) loads; sV free (prev PV done)
            writeV(vreg);              // sV = V(kt)
            if (kt < qt) {
                stageK(kt + 1, (kt + 1) & 1);
                loadV(kt + 1, vreg);
            }

            // St = K * Q^T
            floatx4 st[8][2];
#pragma unroll
            for (int si = 0; si < 8; ++si) {
                short8v a0 = *(const short8v*)&cK[kbase0 + si * 1024];
                short8v a1 = *(const short8v*)&cK[kbase1 + si * 1024];
#pragma unroll
                for (int qi = 0; qi < 2; ++qi) {
                    st[si][qi] = __builtin_amdgcn_mfma_f32_16x16x32_bf16(a0, qf[qi][0], fzero, 0, 0, 0);
                    st[si][qi] = __builtin_amdgcn_mfma_f32_16x16x32_bf16(a1, qf[qi][1], st[si][qi], 0, 0, 0);
                }
            }

            // P = exp2(St)
            short4v pf[8][2];
#pragma unroll
            for (int qi = 0; qi < 2; ++qi) {
                const int qg = q0 + w * 32 + qi * 16 + lq;
                float lsum = 0.f;
#pragma unroll
                for (int si = 0; si < 8; ++si) {
                    float p[4];
#pragma unroll
                    for (int rg = 0; rg < 4; ++rg) {
                        float v = st[si][qi][rg];
                        if (diag) {
                            int sg = kt * 128 + si * 16 + quad * 4 + rg;
                            if (sg > qg) v = -1e30f;
                        }
                        p[rg] = fast_exp2(v);
                        lsum += p[rg];
                    }
                    union { unsigned u[2]; short4v v4; } pk;
                    pk.u[0] = pack_bf16_tr(p[0], p[1]);
                    pk.u[1] = pack_bf16_tr(p[2], p[3]);
                    pf[si][qi] = pk.v4;
                }
                l_i[qi] += lsum;
            }

            __syncthreads();           // sV writes visible

            // O += P*V
#pragma unroll
            for (int ksp = 0; ksp < 8; ++ksp) {
#pragma unroll
                for (int et = 0; et < 4; ++et) {
                    short4v vf = *(const short4v*)&sV[vbase + et * (16 * VROW) + ksp * 16];
#pragma unroll
                    for (int qi = 0; qi < 2; ++qi)
                        o[qi][et] = __builtin_amdgcn_mfma_f32_16x16x16bf16_1k(pf[ksp][qi], vf, o[qi][et], 0, 0, 0);
                }
            }
        }

        // epilogue: reduce l, divide, store Z (B,S,H,DH)
#pragma unroll
        for (int qi = 0; qi < 2; ++qi) {
            float lf = l_i[qi];
            lf += __shfl_xor(lf, 16);
            lf += __shfl_xor(lf, 32);
            float linv[4];
#pragma unroll
            for (int rg = 0; rg < 4; ++rg) linv[rg] = 1.0f / __shfl(lf, quad * 4 + rg);
#pragma unroll
            for (int et = 0; et < 4; ++et) {
#pragma unroll
                for (int rg = 0; rg < 4; ++rg) {
                    int qg = q0 + w * 32 + qi * 16 + quad * 4 + rg;
                    int e = et * 16 + lq;
                    Z[((size_t)(b * S_ + qg) * H_ + h) * DH_ + e] = f2bf(o[qi][et][rg] * linv[rg]);
                }
            }
        }
    }
}

// ---------------- 4. output projection GEMM (operand-swapped, float4 stores) ----------------
__global__ __launch_bounds__(256) void gemm_o(const ushort_t* __restrict__ A,
                                              const ushort_t* __restrict__ Bt,
                                              const float* __restrict__ bias,
                                              float* __restrict__ Dst) {
    __shared__ ushort_t sA[128 * 64];
    __shared__ ushort_t sB[128 * 64];
    const int tid = threadIdx.x;
    const int lane = tid & 63, w = tid >> 6;
    const int lq = lane & 15, quad = lane >> 4;
    const int wm = w >> 1, wn = w & 1;
    const int m0 = blockIdx.x * 128, n0 = blockIdx.y * 128;

    floatx4 acc[4][4] = {};

    for (int k0 = 0; k0 < 1024; k0 += 64) {
        __syncthreads();
#pragma unroll
        for (int p = 0; p < 4; ++p) {
            int rr = w * 32 + p * 8 + (lane >> 3);
            int cc = (lane & 7) ^ (rr & 7);
            g2lds16(&A[(size_t)(m0 + rr) * 1024 + k0 + cc * 8], &sA[(w * 32 + p * 8) * 64]);
            g2lds16(&Bt[(size_t)(n0 + rr) * 1024 + k0 + cc * 8], &sB[(w * 32 + p * 8) * 64]);
        }
        __syncthreads();
#pragma unroll
        for (int ks = 0; ks < 2; ++ks) {
            short8v af[4], bfr[4];
#pragma unroll
            for (int t = 0; t < 4; ++t) {
                int ma = wn * 64 + t * 16 + lq;
                af[t] = *(const short8v*)&sA[ma * 64 + ((((ks << 2) | quad) ^ (ma & 7)) << 3)];
                int nb = wm * 64 + t * 16 + lq;
                bfr[t] = *(const short8v*)&sB[nb * 64 + ((((ks << 2) | quad) ^ (nb & 7)) << 3)];
            }
#pragma unroll
            for (int mt = 0; mt < 4; ++mt)
#pragma unroll
                for (int nt = 0; nt < 4; ++nt)
                    acc[mt][nt] = __builtin_amdgcn_mfma_f32_16x16x32_bf16(bfr[mt], af[nt], acc[mt][nt], 0, 0, 0);
        }
    }

#pragma unroll
    for (int mt = 0; mt < 4; ++mt) {
        int nbase = n0 + wm * 64 + mt * 16 + quad * 4;
        float4 bvv = *(const float4*)&bias[nbase];
        float bb[4] = {bvv.x, bvv.y, bvv.z, bvv.w};
#pragma unroll
        for (int nt = 0; nt < 4; ++nt) {
            int m = m0 + wn * 64 + nt * 16 + lq;
            float4 ov;
            ov.x = acc[mt][nt][0] + bb[0];
            ov.y = acc[mt][nt][1] + bb[1];
            ov.z = acc[mt][nt][2] + bb[2];
            ov.w = acc[mt][nt][3] + bb[3];
            *(float4*)&Dst[(size_t)m * 1024 + nbase] = ov;
        }
    }
}

extern "C" void kernel_launch(void* const* d_in, const int* in_sizes, int n_in,
                              void* d_out, int out_size, void* d_ws, size_t ws_size,
                              hipStream_t stream) {
    const float* x  = (const float*)d_in[0];
    const float* wq = (const float*)d_in[1];
    const float* bq = (const float*)d_in[2];
    const float* wk = (const float*)d_in[3];
    const float* bk = (const float*)d_in[4];
    const float* wv = (const float*)d_in[5];
    const float* bv = (const float*)d_in[6];
    const float* wo = (const float*)d_in[7];
    const float* bo = (const float*)d_in[8];

    char* ws = (char*)d_ws;
    size_t off = 0;
    ushort_t* xb  = (ushort_t*)(ws + off); off += (size_t)8192 * 1024 * 2;
    ushort_t* wt  = (ushort_t*)(ws + off); off += (size_t)3 * 1024 * 1024 * 2;
    ushort_t* wot = (ushort_t*)(ws + off); off += (size_t)1024 * 1024 * 2;
    ushort_t* Qw  = (ushort_t*)(ws + off); off += (size_t)8192 * 1024 * 2;
    ushort_t* Kw  = (ushort_t*)(ws + off); off += (size_t)8192 * 1024 * 2;
    ushort_t* Vw  = (ushort_t*)(ws + off); off += (size_t)8192 * 1024 * 2;
    ushort_t* Zw  = (ushort_t*)(ws + off); off += (size_t)8192 * 1024 * 2;

    prep_kernel<<<12288, 256, 0, stream>>>(x, wq, wk, wv, wo, xb, wt, wot);
    gemm_qkv<<<dim3(64, 24), 256, 0, stream>>>(xb, wt, bq, bk, bv, Qw, Kw, Vw);
    attn_kernel<<<dim3(64, 8), 256, 0, stream>>>(Qw, Kw, Vw, Zw);
    gemm_o<<<dim3(64, 8), 256, 0, stream>>>(Zw, wot, bo, (float*)d_out);
}